// Round 1
// 68.697 us; speedup vs baseline: 1.0268x; 1.0268x over previous
//
#include <hip/hip_runtime.h>
#include <math.h>

// CARAFE: features [2,64,64,128] f32, masks [2,128,128,25] f32 -> out [2,128,128,128] f32
// K=5, k2=25, G=1, Cg=128. Nearest upsample 64->128 half-pixel: src = dst>>1,
// so each 2x2 output quad shares one low-res pixel (r,c) and its 25 patch vectors.
//
// This version removes the latency-bound scattered global loads from the inner
// loop: each block (8 quads = one low-res row segment, cols c0..c0+7) stages its
// UNIQUE 5x12 footprint of feature pixels (60 pixels x 512 B = 30 KB, zero-padded
// at image edges) into LDS with 8 coalesced float4 loads per thread, overlapped
// with the mask softmax. The j-loop is then pure LDS:
//   1 broadcast ds_read_b128 (quad weights) + 1 contiguous ds_read_b128 (features)
//   + 8 v_pk_fma_f32, all compile-time immediate offsets, no bounds checks.
// LDS 30K + 3.2K = 33.3 KB -> 4 blocks/CU, grid 1024 = exactly 4 blocks/CU resident.

#define K   5
#define K2  25
#define QPB 8              // quads per block (same r, consecutive c)
#define TW  (QPB + K - 1)  // 12 tile cols
#define TH  K              // 5  tile rows
#define NPIX (TH * TW)     // 60 staged pixels

typedef float v4f __attribute__((ext_vector_type(4)));

__global__ __launch_bounds__(256) void carafe_tile_kernel(
    const float* __restrict__ feat,   // [B,64,64,128]
    const float* __restrict__ masks,  // [B,128,128,25]
    float* __restrict__ out)          // [B,128,128,128]
{
    __shared__ v4f tile[TH][TW][32];  // 30 KB zero-padded feature tile
    __shared__ v4f wq[QPB][K2];       // 3.2 KB: [quad][j] -> weights of 4 quad pixels

    const int tid   = threadIdx.x;
    const int group = tid >> 5;       // quad slot 0..7 (also: pixel-stage slot)
    const int lane  = tid & 31;       // float4 channel slot (4 ch/lane)

    const int q0  = blockIdx.x * QPB; // first quad of block (multiple of 8, so same b,r)
    const int b   = q0 >> 12;         // / (64*64)
    const int rem = q0 & 4095;
    const int r   = rem >> 6;         // low-res row
    const int c0  = rem & 63;         // first low-res col (multiple of 8)

    // ---- issue the 8 coalesced feature-tile loads first (independent, in flight)
    const v4f* featv = (const v4f*)feat;          // 32 float4 per low-res pixel
    const size_t fbase = (size_t)b * (64 * 64 * 32);

    v4f stg[8];
    #pragma unroll
    for (int i = 0; i < 8; ++i) {
        const int p = group + i * 8;              // staged pixel 0..63 (need < 60)
        v4f v = 0.f;
        if (p < NPIX) {
            const int row = p / TW;               // 0..4
            const int col = p - row * TW;         // 0..11
            const int gr  = r  - 2 + row;
            const int gc  = c0 - 2 + col;
            if ((unsigned)gr < 64u && (unsigned)gc < 64u)
                v = featv[fbase + (size_t)(gr * 64 + gc) * 32 + lane];
        }
        stg[i] = v;                               // zero-padded at edges
    }

    // ---- 4 softmaxes over 25 mask logits (lane j holds logit j for j<25);
    //      mask-load latency hides under the feature loads above
    const int pix00 = ((b * 128 + 2 * r) * 128 + 2 * (c0 + group));
    const int pixofs[4] = {0, 1, 128, 129};

    float w[4];
    #pragma unroll
    for (int p = 0; p < 4; ++p) {
        const int pix = pix00 + pixofs[p];
        float mv = (lane < K2) ? masks[(size_t)pix * K2 + lane] : -INFINITY;
        float mx = mv;
        #pragma unroll
        for (int off = 16; off >= 1; off >>= 1)
            mx = fmaxf(mx, __shfl_xor(mx, off, 32));
        float e = (lane < K2) ? __expf(mv - mx) : 0.0f;
        float s = e;
        #pragma unroll
        for (int off = 16; off >= 1; off >>= 1)
            s += __shfl_xor(s, off, 32);
        w[p] = e / s;
    }

    // ---- commit staged tile + weights to LDS
    #pragma unroll
    for (int i = 0; i < 8; ++i) {
        const int p = group + i * 8;
        if (p < NPIX)
            ((v4f*)tile)[p * 32 + lane] = stg[i];  // contiguous 512B per half-wave
    }
    if (lane < K2) {
        float* dst = (float*)&wq[group][lane];
        dst[0] = w[0]; dst[1] = w[1]; dst[2] = w[2]; dst[3] = w[3];
    }
    __syncthreads();

    // ---- pure-LDS weighted accumulation: no bounds checks, immediate offsets
    v4f acc0 = 0.f, acc1 = 0.f, acc2 = 0.f, acc3 = 0.f;
    #pragma unroll
    for (int j = 0; j < K2; ++j) {
        const int di = j / K;
        const int dj = j % K;
        const v4f wj = wq[group][j];               // broadcast within 32-lane group
        const v4f f  = tile[di][group + dj][lane]; // contiguous b128, conflict-benign
        acc0 += f * wj.x;
        acc1 += f * wj.y;
        acc2 += f * wj.z;
        acc3 += f * wj.w;
    }

    // ---- write the 4 output pixels (512 B coalesced per group)
    v4f* outv = (v4f*)out;
    outv[(size_t)(pix00 +   0) * 32 + lane] = acc0;
    outv[(size_t)(pix00 +   1) * 32 + lane] = acc1;
    outv[(size_t)(pix00 + 128) * 32 + lane] = acc2;
    outv[(size_t)(pix00 + 129) * 32 + lane] = acc3;
}

extern "C" void kernel_launch(void* const* d_in, const int* in_sizes, int n_in,
                              void* d_out, int out_size, void* d_ws, size_t ws_size,
                              hipStream_t stream) {
    const float* feat  = (const float*)d_in[0];   // 2*64*64*128
    const float* masks = (const float*)d_in[1];   // 2*128*128*25
    float* out = (float*)d_out;                   // 2*128*128*128

    // quads = B * 64 * 64 = 8192; 8 quads (256 threads) per block
    dim3 grid((2 * 64 * 64) / QPB), block(256);
    carafe_tile_kernel<<<grid, block, 0, stream>>>(feat, masks, out);
}